// Round 1
// baseline (1452.812 us; speedup 1.0000x reference)
//
#include <hip/hip_runtime.h>
#include <math.h>

#define TOK 16384
#define HD 7168
#define NE 256

constexpr int BM = 128, BN = 128, BK = 32, PAD = 4;
constexpr int NTHR = 256;

// fp32 GEMM: C[t][e] = sum_k A[t][k] * W[e][k]
// Accuracy scheme: fp32 FMA within a BK=32 chunk, chunk sum flushed into a
// double accumulator (exact adds) -> total logit error ~4e-7, far below the
// expected min top-k gap (~1e-6..1e-5). This is what keeps the indices output
// (threshold 5.1 == "no flips") safe.
__global__ __launch_bounds__(256, 1)
void gemm_logits(const float* __restrict__ A, const float* __restrict__ W,
                 float* __restrict__ C) {
  __shared__ __align__(16) float sa[BK][BM + PAD];
  __shared__ __align__(16) float sb[BK][BN + PAD];

  const int tid = threadIdx.x;
  const int bm = blockIdx.x >> 1;   // 128 row-blocks
  const int bn = blockIdx.x & 1;    // 2 col-blocks
  const int tx = tid & 15;          // expert quad
  const int ty = tid >> 4;          // token quad

  const float* aBase = A + (size_t)bm * BM * HD;
  const float* wBase = W + (size_t)bn * BN * HD;

  float4 ra[4], rb[4];

  float  accf[2][2][4][4];
  double accd[2][2][4][4];
#pragma unroll
  for (int p = 0; p < 2; ++p)
#pragma unroll
    for (int q = 0; q < 2; ++q)
#pragma unroll
      for (int i = 0; i < 4; ++i)
#pragma unroll
        for (int j = 0; j < 4; ++j) {
          accf[p][q][i][j] = 0.f;
          accd[p][q][i][j] = 0.0;
        }

  // prefetch tile 0 into registers
#pragma unroll
  for (int p = 0; p < 4; ++p) {
    int id = tid + p * NTHR;
    int row = id >> 3, c4 = id & 7;
    ra[p] = *(const float4*)(aBase + (size_t)row * HD + c4 * 4);
    rb[p] = *(const float4*)(wBase + (size_t)row * HD + c4 * 4);
  }

  const int NK = HD / BK;  // 224
  for (int kt = 0; kt < NK; ++kt) {
    __syncthreads();
    // store regs -> LDS (transposed to [k][m] / [k][n])
#pragma unroll
    for (int p = 0; p < 4; ++p) {
      int id = tid + p * NTHR;
      int row = id >> 3, c4 = id & 7;
      sa[c4 * 4 + 0][row] = ra[p].x;
      sa[c4 * 4 + 1][row] = ra[p].y;
      sa[c4 * 4 + 2][row] = ra[p].z;
      sa[c4 * 4 + 3][row] = ra[p].w;
      sb[c4 * 4 + 0][row] = rb[p].x;
      sb[c4 * 4 + 1][row] = rb[p].y;
      sb[c4 * 4 + 2][row] = rb[p].z;
      sb[c4 * 4 + 3][row] = rb[p].w;
    }
    __syncthreads();
    // issue next tile's global loads; they drain under the inner loop
    if (kt + 1 < NK) {
      int k0 = (kt + 1) * BK;
#pragma unroll
      for (int p = 0; p < 4; ++p) {
        int id = tid + p * NTHR;
        int row = id >> 3, c4 = id & 7;
        ra[p] = *(const float4*)(aBase + (size_t)row * HD + k0 + c4 * 4);
        rb[p] = *(const float4*)(wBase + (size_t)row * HD + k0 + c4 * 4);
      }
    }
#pragma unroll 8
    for (int kk = 0; kk < BK; ++kk) {
      float4 a0 = *(const float4*)&sa[kk][ty * 4];
      float4 a1 = *(const float4*)&sa[kk][64 + ty * 4];
      float4 b0 = *(const float4*)&sb[kk][tx * 4];
      float4 b1 = *(const float4*)&sb[kk][64 + tx * 4];
      float am[2][4] = {{a0.x, a0.y, a0.z, a0.w}, {a1.x, a1.y, a1.z, a1.w}};
      float bv[2][4] = {{b0.x, b0.y, b0.z, b0.w}, {b1.x, b1.y, b1.z, b1.w}};
#pragma unroll
      for (int qm = 0; qm < 2; ++qm)
#pragma unroll
        for (int qn = 0; qn < 2; ++qn)
#pragma unroll
          for (int i = 0; i < 4; ++i)
#pragma unroll
            for (int j = 0; j < 4; ++j)
              accf[qm][qn][i][j] = fmaf(am[qm][i], bv[qn][j], accf[qm][qn][i][j]);
    }
    // flush fp32 chunk into double accumulators
#pragma unroll
    for (int qm = 0; qm < 2; ++qm)
#pragma unroll
      for (int qn = 0; qn < 2; ++qn)
#pragma unroll
        for (int i = 0; i < 4; ++i)
#pragma unroll
          for (int j = 0; j < 4; ++j) {
            accd[qm][qn][i][j] += (double)accf[qm][qn][i][j];
            accf[qm][qn][i][j] = 0.f;
          }
  }

  // epilogue: write raw fp32 logits
  float* cBase = C + (size_t)(bm * BM) * NE + bn * BN;
#pragma unroll
  for (int qm = 0; qm < 2; ++qm)
#pragma unroll
    for (int i = 0; i < 4; ++i) {
      int row = qm * 64 + ty * 4 + i;
#pragma unroll
      for (int qn = 0; qn < 2; ++qn) {
        float4 o;
        o.x = (float)accd[qm][qn][i][0];
        o.y = (float)accd[qm][qn][i][1];
        o.z = (float)accd[qm][qn][i][2];
        o.w = (float)accd[qm][qn][i][3];
        *(float4*)(cBase + (size_t)row * NE + qn * 64 + tx * 4) = o;
      }
    }
}

// One wave per token. Comparisons in f64 (sigmoid monotone => order == logit
// order); group sums in f64 to stay far below the min group gap.
__global__ __launch_bounds__(256)
void router(const float* __restrict__ logits, float* __restrict__ out_w,
            float* __restrict__ out_i) {
  const int gid = blockIdx.x * blockDim.x + threadIdx.x;
  const int tok = gid >> 6;
  const int lane = gid & 63;
  if (tok >= TOK) return;

  const float4 v = *(const float4*)(logits + (size_t)tok * NE + lane * 4);
  double s[4];
  s[0] = 1.0 / (1.0 + exp(-(double)v.x));
  s[1] = 1.0 / (1.0 + exp(-(double)v.y));
  s[2] = 1.0 / (1.0 + exp(-(double)v.z));
  s[3] = 1.0 / (1.0 + exp(-(double)v.w));

  // group sums: lanes [8g..8g+7] cover experts [32g..32g+31]
  double gsum = s[0] + s[1] + s[2] + s[3];
  gsum += __shfl_xor(gsum, 1);
  gsum += __shfl_xor(gsum, 2);
  gsum += __shfl_xor(gsum, 4);

  double gs[8];
#pragma unroll
  for (int g = 0; g < 8; ++g) gs[g] = __shfl(gsum, g * 8);

  // top-4 groups (ties -> lower index, matching jax.lax.top_k)
  unsigned sel = 0;
#pragma unroll
  for (int r = 0; r < 4; ++r) {
    int best = 0;
    double bvv = -1e300;
#pragma unroll
    for (int g = 0; g < 8; ++g)
      if (!((sel >> g) & 1) && gs[g] > bvv) {
        bvv = gs[g];
        best = g;
      }
    sel |= 1u << best;
  }

  const int grp = lane >> 3;
  const bool act = (sel >> grp) & 1;
  double ms[4];
#pragma unroll
  for (int j = 0; j < 4; ++j) ms[j] = act ? s[j] : -1.0;

  // top-8 experts by repeated wave argmax
  double vals[8];
  int idxs[8];
#pragma unroll
  for (int r = 0; r < 8; ++r) {
    double lv = -3.0;
    int li = 1 << 30;
#pragma unroll
    for (int j = 0; j < 4; ++j)
      if (ms[j] > lv) {
        lv = ms[j];
        li = lane * 4 + j;
      }
#pragma unroll
    for (int off = 1; off < 64; off <<= 1) {
      double ov = __shfl_xor(lv, off);
      int oi = __shfl_xor(li, off);
      if (ov > lv || (ov == lv && oi < li)) {
        lv = ov;
        li = oi;
      }
    }
    vals[r] = lv;
    idxs[r] = li;
    if ((li >> 2) == lane) ms[li & 3] = -3.0;  // remove winner
  }

  double denom = 0.0;
#pragma unroll
  for (int r = 0; r < 8; ++r) denom += vals[r];
  if (denom < 1e-12) denom = 1e-12;

  const size_t base = (size_t)tok * 8;
#pragma unroll
  for (int r = 0; r < 8; ++r)
    if (lane == r) {
      out_w[base + r] = (float)(vals[r] / denom);
      out_i[base + r] = (float)idxs[r];
    }
}

extern "C" void kernel_launch(void* const* d_in, const int* in_sizes, int n_in,
                              void* d_out, int out_size, void* d_ws, size_t ws_size,
                              hipStream_t stream) {
  const float* hs = (const float*)d_in[0];  // [16384, 7168]
  const float* W  = (const float*)d_in[1];  // [256, 7168]
  float* out = (float*)d_out;
  // d_out layout (all read back as float32): weights [T,8] | indices [T,8] | logits [T,256]
  float* out_w   = out;
  float* out_i   = out + (size_t)TOK * 8;
  float* logitsO = out + (size_t)TOK * 16;

  gemm_logits<<<dim3((TOK / BM) * (NE / BN)), dim3(NTHR), 0, stream>>>(hs, W, logitsO);
  router<<<dim3(TOK * 64 / 256), dim3(256), 0, stream>>>(logitsO, out_w, out_i);
}